// Round 11
// baseline (1075.126 us; speedup 1.0000x reference)
//
#include <hip/hip_runtime.h>

// DeepRLSNet: batched RLS. B=64, N=T=2000, TAPS=64.
// Per step:
//   lam = clip(lambdas[t], 1e-4, 0.9999)
//   Px = P@x ; den = lam + x.Px ; g = Px/den ; y = w.x
//   w += g*(d-y) ; P = (P - outer(g, x@P))/lam   (honest x@P — R2 post-mortem)
//
// R11 = R9's two-steps-per-round Sherman-Morrison kernel with NUMERICS
// PRESERVED BIT-FOR-BIT (explicit dual rank-1 updates; QT stays bitwise
// == Q^T because both sides use identical fused products of bitwise-shared
// broadcast values; rcp_nr on the den chain) + mechanical fixes only:
//  - LDS vector stride 64 -> 72: scatter write banks r+8q, 2-way max (free);
//    R9 had 4-way conflicts (1.54M SQ_LDS_BANK_CONFLICT).
//  - clip(lam) & rcp_nr(lam) precomputed to an LDS table (same bits as R9's
//    in-loop computation, hoisted off the critical path). d staged likewise.
//  - running-pointer unclamped prefetch; loop bounds give FULL round
//    coverage 0..1998 (R10 skipped rounds 1992/1994 — bug).
// sigma-space: P = sig*Q, sig *= (1/lam0)*(1/lam1) per round.
// 64 blocks x 256 threads; thread t=r*4+q owns 16-wide quarter-rows of Q,QT.

#define B_ 64
#define N_ 2000
#define TAPS_ 64
#define STEPS_ 2000
#define VST_ 72   // padded LDS vector stride (floats); 72%32=8 -> 2-way banks

__device__ __forceinline__ void lds_barrier() {
    // LDS-only fence + barrier: global (vmcnt) prefetch stays in flight.
    asm volatile("s_waitcnt lgkmcnt(0)\n\ts_barrier" ::: "memory");
}

__device__ __forceinline__ float clipl(float v) {
    return fminf(fmaxf(v, 1e-4f), 0.9999f);
}

// sum over the 4 q-lanes of a quad via DPP quad_perm (VALU-latency class).
__device__ __forceinline__ float quad_reduce(float v) {
    int t1 = __builtin_amdgcn_update_dpp(__float_as_int(v), __float_as_int(v),
                                         0xB1, 0xF, 0xF, false);   // xor 1
    v += __int_as_float(t1);
    int t2 = __builtin_amdgcn_update_dpp(__float_as_int(v), __float_as_int(v),
                                         0x4E, 0xF, 0xF, false);   // xor 2
    v += __int_as_float(t2);
    return v;   // bitwise-identical in all 4 lanes of the quad
}

// 1/v via v_rcp_f32 + one Newton step (~0.5 ulp).
__device__ __forceinline__ float rcp_nr(float v) {
    float r = __builtin_amdgcn_rcpf(v);
    float e = fmaf(-v, r, 1.0f);
    return fmaf(r, e, r);
}

__global__ __launch_bounds__(256, 1) void rls_kernel(
    const float* __restrict__ x_seq,   // [B, N, TAPS]
    const float* __restrict__ d_seq,   // [B, N]
    const float* __restrict__ lambdas, // [T]
    float* __restrict__ y_out,         // [B, N]
    float* __restrict__ w_out)         // [B, TAPS]
{
    const int b   = blockIdx.x;
    const int tid = threadIdx.x;
    const int r   = tid >> 2;    // row 0..63
    const int q   = tid & 3;     // quarter 0..3
    const int qb  = q << 4;

    // [parity][vec][VST_], vec: 0=Qx 1=xQ 2=u 3=v
    __shared__ __align__(16) float  bufs[2][4][VST_];
    __shared__ __align__(16) float  d_lds[STEPS_];
    __shared__ __align__(16) float2 lam2[STEPS_];   // {clip(lam), rcp_nr(clip(lam))}

    const float* xb = x_seq + (size_t)b * N_ * TAPS_;
    const float* db = d_seq + (size_t)b * N_;

    for (int idx = tid; idx < STEPS_; idx += 256) {
        d_lds[idx] = db[idx];
        const float lc = clipl(lambdas[idx]);
        lam2[idx] = make_float2(lc, rcp_nr(lc));
    }

    float Q[16], QT[16], w[16];
    #pragma unroll
    for (int j = 0; j < 16; ++j) {
        const float id = (qb + j == r) ? 1.0f : 0.0f;
        Q[j] = id; QT[j] = id; w[j] = 0.0f;
    }
    float sig = 1.0f;   // P = sig * Q

    float xA[16], xB[16], xC[16], xD[16];
    {
        const float4* v0 = (const float4*)(xb + qb);
        const float4* v1 = (const float4*)(xb + TAPS_ + qb);
        #pragma unroll
        for (int j4 = 0; j4 < 4; ++j4) {
            float4 a4 = v0[j4], b4 = v1[j4];
            xA[j4*4+0]=a4.x; xA[j4*4+1]=a4.y; xA[j4*4+2]=a4.z; xA[j4*4+3]=a4.w;
            xB[j4*4+0]=b4.x; xB[j4*4+1]=b4.y; xB[j4*4+2]=b4.z; xB[j4*4+3]=b4.w;
        }
    }
    const float* xp = xb + 2 * TAPS_ + qb;   // running prefetch ptr (row t+2)

    lds_barrier();   // d_lds / lam2 visible

    // one round = steps t, t+1 (x0=x_t, x1=x_{t+1}); prefetches rows t+2,t+3.
    auto round = [&](int t, float (&x0)[16], float (&x1)[16],
                     float (&xp0)[16], float (&xp1)[16], int par, bool pf) {
        // ---- 4 shared-vector dots first (write ASAP) ----
        float qxr = 0.f, xqr = 0.f, ur = 0.f, vr = 0.f;
        #pragma unroll
        for (int j = 0; j < 16; ++j) {
            qxr = fmaf(Q[j],  x0[j], qxr);
            xqr = fmaf(QT[j], x0[j], xqr);
            ur  = fmaf(Q[j],  x1[j], ur);
            vr  = fmaf(QT[j], x1[j], vr);
        }
        qxr = quad_reduce(qxr);  xqr = quad_reduce(xqr);
        ur  = quad_reduce(ur);   vr  = quad_reduce(vr);
        {
            const float val = (q == 0) ? qxr : (q == 1) ? xqr : (q == 2) ? ur : vr;
            bufs[par][q][r] = val;   // banks r+8q: 2-way max (free)
        }

        // ---- w dots while the write drains ----
        float wy0 = 0.f, wy1 = 0.f;
        #pragma unroll
        for (int j = 0; j < 16; ++j) {
            wy0 = fmaf(w[j], x0[j], wy0);
            wy1 = fmaf(w[j], x1[j], wy1);
        }
        wy0 = quad_reduce(wy0);
        wy1 = quad_reduce(wy1);

        lds_barrier();

        // ---- prefetch next round's x rows (rides across raw barriers) ----
        if (pf) {
            const float4* v0 = (const float4*)xp;
            const float4* v1 = (const float4*)(xp + TAPS_);
            #pragma unroll
            for (int j4 = 0; j4 < 4; ++j4) {
                float4 a4 = v0[j4], b4 = v1[j4];
                xp0[j4*4+0]=a4.x; xp0[j4*4+1]=a4.y; xp0[j4*4+2]=a4.z; xp0[j4*4+3]=a4.w;
                xp1[j4*4+0]=b4.x; xp1[j4*4+1]=b4.y; xp1[j4*4+2]=b4.z; xp1[j4*4+3]=b4.w;
            }
            xp += 2 * TAPS_;
        }

        // ---- read back quarters of Qx, xQ, u, v ----
        float Qxq[16], xQq[16], uq[16], vq[16];
        {
            const float4* p0 = (const float4*)(&bufs[par][0][qb]);
            const float4* p1 = (const float4*)(&bufs[par][1][qb]);
            const float4* p2 = (const float4*)(&bufs[par][2][qb]);
            const float4* p3 = (const float4*)(&bufs[par][3][qb]);
            #pragma unroll
            for (int j4 = 0; j4 < 4; ++j4) {
                float4 a4 = p0[j4], b4 = p1[j4], c4 = p2[j4], e4 = p3[j4];
                Qxq[j4*4+0]=a4.x; Qxq[j4*4+1]=a4.y; Qxq[j4*4+2]=a4.z; Qxq[j4*4+3]=a4.w;
                xQq[j4*4+0]=b4.x; xQq[j4*4+1]=b4.y; xQq[j4*4+2]=b4.z; xQq[j4*4+3]=b4.w;
                uq [j4*4+0]=c4.x; uq [j4*4+1]=c4.y; uq [j4*4+2]=c4.z; uq [j4*4+3]=c4.w;
                vq [j4*4+0]=e4.x; vq [j4*4+1]=e4.y; vq [j4*4+2]=e4.z; vq [j4*4+3]=e4.w;
            }
        }

        // ---- post-barrier quarter-dots: pd0=x0.Qx, a=x1.xQ, bb=x1.Qx, c2=x1.u ----
        float pd0 = 0.f, a = 0.f, bb = 0.f, c2 = 0.f;
        #pragma unroll
        for (int j = 0; j < 16; ++j) {
            pd0 = fmaf(x0[j], Qxq[j], pd0);
            a   = fmaf(x1[j], xQq[j], a);
            bb  = fmaf(x1[j], Qxq[j], bb);
            c2  = fmaf(x1[j], uq[j],  c2);
        }
        pd0 = quad_reduce(pd0);  a  = quad_reduce(a);
        bb  = quad_reduce(bb);   c2 = quad_reduce(c2);

        // ---- scalars (R9 op order, rcp_nr on dens) ----
        const float2 l0 = lam2[t];
        const float2 l1 = lam2[t + 1];
        const float2 dd = *(const float2*)&d_lds[t];

        const float den0 = fmaf(sig, pd0, l0.x);
        const float s0   = sig * rcp_nr(den0);
        const float err0 = dd.x - wy0;
        const float es0  = s0 * err0;
        const float sa   = s0 * a;
        const float sb   = s0 * bb;

        const float sig1 = sig * l0.y;
        const float pd1  = fmaf(-sa, bb, c2);
        const float den1 = fmaf(sig1, pd1, l1.x);
        const float s1   = sig1 * rcp_nr(den1);
        const float y1   = fmaf(es0, bb, wy1);
        const float err1 = dd.y - y1;
        const float es1  = s1 * err1;
        sig = sig1 * l1.y;

        if (tid == 0)
            *(float2*)(y_out + (size_t)b * N_ + t) = make_float2(wy0, y1);

        // ---- R9 explicit dual rank-1 updates (bitwise QT == Q^T) ----
        const float qx1r = fmaf(-sa, qxr, ur);
        const float xq1r = fmaf(-sb, xqr, vr);
        const float tr0  = s0 * qxr;
        const float tr1  = s1 * qx1r;

        #pragma unroll
        for (int j = 0; j < 16; ++j) {
            const float Qx1 = fmaf(-sa, Qxq[j], uq[j]);   // Qx1[c]
            const float xQ1 = fmaf(-sb, xQq[j], vq[j]);   // xQ1[c]
            const float tq0 = s0 * Qxq[j];
            const float tq1 = s1 * Qx1;
            // w: two honest rank-1 adds
            w[j] = fmaf(Qxq[j], es0, w[j]);
            w[j] = fmaf(Qx1,    es1, w[j]);
            // Q row r: subtract both outer-product terms
            Q[j] = fmaf(-tr0, xQq[j], Q[j]);
            Q[j] = fmaf(-tr1, xQ1,    Q[j]);
            // QT row r (= Q column r): transposed products, identical bits
            QT[j] = fmaf(-tq0, xqr,  QT[j]);
            QT[j] = fmaf(-tq1, xq1r, QT[j]);
        }
    };

    // main rounds: t = 0,4,...,1992 -> rounds 0..1994 (prefetch <= row 1997)
    for (int t = 0; t < STEPS_ - 4; t += 4) {
        round(t + 0, xA, xB, xC, xD, 0, true);
        round(t + 2, xC, xD, xA, xB, 1, true);
    }
    // epilogue: round 1996 prefetches rows 1998,1999; round 1998 none
    round(STEPS_ - 4, xA, xB, xC, xD, 0, true);
    round(STEPS_ - 2, xC, xD, xA, xB, 1, false);

    // ---- final weights: row-group 0 holds a full replica across q ----
    if (r == 0) {
        float4* wo = (float4*)(w_out + (size_t)b * TAPS_ + qb);
        #pragma unroll
        for (int j4 = 0; j4 < 4; ++j4)
            wo[j4] = make_float4(w[j4*4+0], w[j4*4+1], w[j4*4+2], w[j4*4+3]);
    }
}

extern "C" void kernel_launch(void* const* d_in, const int* in_sizes, int n_in,
                              void* d_out, int out_size, void* d_ws, size_t ws_size,
                              hipStream_t stream) {
    const float* x_seq   = (const float*)d_in[0];
    const float* d_seq   = (const float*)d_in[1];
    const float* lambdas = (const float*)d_in[2];

    float* y_out = (float*)d_out;                      // B*N floats
    float* w_out = (float*)d_out + (size_t)B_ * N_;    // B*TAPS floats

    rls_kernel<<<B_, 256, 0, stream>>>(x_seq, d_seq, lambdas, y_out, w_out);
}

// Round 12
// 1026.152 us; speedup vs baseline: 1.0477x; 1.0477x over previous
//
#include <hip/hip_runtime.h>

// DeepRLSNet: batched RLS. B=64, N=T=2000, TAPS=64.
// Per step:
//   lam = clip(lambdas[t], 1e-4, 0.9999)
//   Px = P@x ; den = lam + x.Px ; g = Px/den ; y = w.x
//   w += g*(d-y) ; P = (P - outer(g, x@P))/lam   (honest x@P — R2 post-mortem)
//
// R12 = R11 (two-steps-per-round Sherman-Morrison, bitwise QT==Q^T explicit
// dual rank-1 updates — the R10/R11 bisect proved the bitwise invariant is
// load-bearing) with all 16-element per-thread loops converted to float2
// ext-vectors + __builtin_elementwise_fma -> v_pk_fma_f32 (2x fp32 issue
// rate on CDNA4; the 157.3 TF peak is the packed rate). pk_fma's lanes are
// exact IEEE fma -> per-element update math is bitwise identical to R11;
// only dot-reduction order changes (pairwise, lane-uniform).
// sigma-space: P = sig*Q, sig *= (1/lam0)*(1/lam1) per round.
// 64 blocks x 256 threads; thread t=r*4+q owns 16-wide quarter-rows of Q,QT.

#define B_ 64
#define N_ 2000
#define TAPS_ 64
#define STEPS_ 2000
#define VST_ 72   // padded LDS vector stride; banks r+8q -> 2-way max (free)

typedef float f2 __attribute__((ext_vector_type(2)));

__device__ __forceinline__ f2 pk2(float v) { f2 r; r.x = v; r.y = v; return r; }

__device__ __forceinline__ void lds_barrier() {
    // LDS-only fence + barrier: global (vmcnt) prefetch stays in flight.
    asm volatile("s_waitcnt lgkmcnt(0)\n\ts_barrier" ::: "memory");
}

__device__ __forceinline__ float clipl(float v) {
    return fminf(fmaxf(v, 1e-4f), 0.9999f);
}

// sum over the 4 q-lanes of a quad via DPP quad_perm (VALU-latency class).
__device__ __forceinline__ float quad_reduce(float v) {
    int t1 = __builtin_amdgcn_update_dpp(__float_as_int(v), __float_as_int(v),
                                         0xB1, 0xF, 0xF, false);   // xor 1
    v += __int_as_float(t1);
    int t2 = __builtin_amdgcn_update_dpp(__float_as_int(v), __float_as_int(v),
                                         0x4E, 0xF, 0xF, false);   // xor 2
    v += __int_as_float(t2);
    return v;   // bitwise-identical in all 4 lanes of the quad
}

// 1/v via v_rcp_f32 + one Newton step (~0.5 ulp).
__device__ __forceinline__ float rcp_nr(float v) {
    float r = __builtin_amdgcn_rcpf(v);
    float e = fmaf(-v, r, 1.0f);
    return fmaf(r, e, r);
}

__global__ __launch_bounds__(256, 1) void rls_kernel(
    const float* __restrict__ x_seq,   // [B, N, TAPS]
    const float* __restrict__ d_seq,   // [B, N]
    const float* __restrict__ lambdas, // [T]
    float* __restrict__ y_out,         // [B, N]
    float* __restrict__ w_out)         // [B, TAPS]
{
    const int b   = blockIdx.x;
    const int tid = threadIdx.x;
    const int r   = tid >> 2;    // row 0..63
    const int q   = tid & 3;     // quarter 0..3
    const int qb  = q << 4;

    // [parity][vec][VST_], vec: 0=Qx 1=xQ 2=u 3=v
    __shared__ __align__(16) float  bufs[2][4][VST_];
    __shared__ __align__(16) float  d_lds[STEPS_];
    __shared__ __align__(16) float2 lam2[STEPS_];   // {clip(lam), rcp_nr(clip(lam))}

    const float* xb = x_seq + (size_t)b * N_ * TAPS_;
    const float* db = d_seq + (size_t)b * N_;

    for (int idx = tid; idx < STEPS_; idx += 256) {
        d_lds[idx] = db[idx];
        const float lc = clipl(lambdas[idx]);
        lam2[idx] = make_float2(lc, rcp_nr(lc));
    }

    f2 Q[8], QT[8], w[8];
    #pragma unroll
    for (int j = 0; j < 8; ++j) {
        Q[j].x = (qb + 2*j     == r) ? 1.0f : 0.0f;
        Q[j].y = (qb + 2*j + 1 == r) ? 1.0f : 0.0f;
        QT[j] = Q[j];
        w[j]  = pk2(0.0f);
    }
    float sig = 1.0f;   // P = sig * Q

    auto unpack4 = [](f2* dst, float4 v) {
        dst[0].x = v.x; dst[0].y = v.y; dst[1].x = v.z; dst[1].y = v.w;
    };

    f2 xA[8], xB[8], xC[8], xD[8];
    {
        const float4* v0 = (const float4*)(xb + qb);
        const float4* v1 = (const float4*)(xb + TAPS_ + qb);
        #pragma unroll
        for (int j4 = 0; j4 < 4; ++j4) {
            unpack4(&xA[2*j4], v0[j4]);
            unpack4(&xB[2*j4], v1[j4]);
        }
    }
    const float* xp = xb + 2 * TAPS_ + qb;   // running prefetch ptr (row t+2)

    lds_barrier();   // d_lds / lam2 visible

    // one round = steps t, t+1 (x0=x_t, x1=x_{t+1}); prefetches rows t+2,t+3.
    auto round = [&](int t, f2 (&x0)[8], f2 (&x1)[8],
                     f2 (&xp0)[8], f2 (&xp1)[8], int par, bool pf) {
        // ---- 4 shared-vector dots first (write ASAP) ----
        f2 qx2 = pk2(0.f), xq2 = pk2(0.f), u2 = pk2(0.f), v2 = pk2(0.f);
        #pragma unroll
        for (int j = 0; j < 8; ++j) {
            qx2 = __builtin_elementwise_fma(Q[j],  x0[j], qx2);
            xq2 = __builtin_elementwise_fma(QT[j], x0[j], xq2);
            u2  = __builtin_elementwise_fma(Q[j],  x1[j], u2);
            v2  = __builtin_elementwise_fma(QT[j], x1[j], v2);
        }
        const float qxr = quad_reduce(qx2.x + qx2.y);
        const float xqr = quad_reduce(xq2.x + xq2.y);
        const float ur  = quad_reduce(u2.x + u2.y);
        const float vr  = quad_reduce(v2.x + v2.y);
        {
            const float val = (q == 0) ? qxr : (q == 1) ? xqr : (q == 2) ? ur : vr;
            bufs[par][q][r] = val;   // banks r+8q: 2-way max (free)
        }

        // ---- w dots while the write drains ----
        f2 wy02 = pk2(0.f), wy12 = pk2(0.f);
        #pragma unroll
        for (int j = 0; j < 8; ++j) {
            wy02 = __builtin_elementwise_fma(w[j], x0[j], wy02);
            wy12 = __builtin_elementwise_fma(w[j], x1[j], wy12);
        }
        const float wy0 = quad_reduce(wy02.x + wy02.y);
        const float wy1 = quad_reduce(wy12.x + wy12.y);

        lds_barrier();

        // ---- prefetch next round's x rows (rides across raw barriers) ----
        if (pf) {
            const float4* v0 = (const float4*)xp;
            const float4* v1 = (const float4*)(xp + TAPS_);
            #pragma unroll
            for (int j4 = 0; j4 < 4; ++j4) {
                unpack4(&xp0[2*j4], v0[j4]);
                unpack4(&xp1[2*j4], v1[j4]);
            }
            xp += 2 * TAPS_;
        }

        // ---- read back quarters of Qx, xQ, u, v ----
        f2 Qxq[8], xQq[8], uq[8], vq[8];
        {
            const float4* p0 = (const float4*)(&bufs[par][0][qb]);
            const float4* p1 = (const float4*)(&bufs[par][1][qb]);
            const float4* p2 = (const float4*)(&bufs[par][2][qb]);
            const float4* p3 = (const float4*)(&bufs[par][3][qb]);
            #pragma unroll
            for (int j4 = 0; j4 < 4; ++j4) {
                unpack4(&Qxq[2*j4], p0[j4]);
                unpack4(&xQq[2*j4], p1[j4]);
                unpack4(&uq [2*j4], p2[j4]);
                unpack4(&vq [2*j4], p3[j4]);
            }
        }

        // ---- post-barrier dots: pd0=x0.Qx, a=x1.xQ, bb=x1.Qx, c2=x1.u ----
        f2 pd2 = pk2(0.f), a2 = pk2(0.f), bb2 = pk2(0.f), c22 = pk2(0.f);
        #pragma unroll
        for (int j = 0; j < 8; ++j) {
            pd2 = __builtin_elementwise_fma(x0[j], Qxq[j], pd2);
            a2  = __builtin_elementwise_fma(x1[j], xQq[j], a2);
            bb2 = __builtin_elementwise_fma(x1[j], Qxq[j], bb2);
            c22 = __builtin_elementwise_fma(x1[j], uq[j],  c22);
        }
        const float pd0 = quad_reduce(pd2.x + pd2.y);
        const float a   = quad_reduce(a2.x + a2.y);
        const float bb  = quad_reduce(bb2.x + bb2.y);
        const float c2  = quad_reduce(c22.x + c22.y);

        // ---- scalars (R11 op order, rcp_nr on dens) ----
        const float2 l0 = lam2[t];
        const float2 l1 = lam2[t + 1];
        const float2 dd = *(const float2*)&d_lds[t];

        const float den0 = fmaf(sig, pd0, l0.x);
        const float s0   = sig * rcp_nr(den0);
        const float err0 = dd.x - wy0;
        const float es0  = s0 * err0;
        const float sa   = s0 * a;
        const float sb   = s0 * bb;

        const float sig1 = sig * l0.y;
        const float pd1  = fmaf(-sa, bb, c2);
        const float den1 = fmaf(sig1, pd1, l1.x);
        const float s1   = sig1 * rcp_nr(den1);
        const float y1   = fmaf(es0, bb, wy1);
        const float err1 = dd.y - y1;
        const float es1  = s1 * err1;
        sig = sig1 * l1.y;

        if (tid == 0)
            *(float2*)(y_out + (size_t)b * N_ + t) = make_float2(wy0, y1);

        // ---- explicit dual rank-1 updates (bitwise QT == Q^T preserved:
        //      pk_fma lanes are exact IEEE fma on the same shared bits) ----
        const float qx1r = fmaf(-sa, qxr, ur);
        const float xq1r = fmaf(-sb, xqr, vr);
        const f2 nsa   = pk2(-sa);
        const f2 nsb   = pk2(-sb);
        const f2 s0v   = pk2(s0);
        const f2 s1v   = pk2(s1);
        const f2 es0v  = pk2(es0);
        const f2 es1v  = pk2(es1);
        const f2 ntr0  = pk2(-(s0 * qxr));
        const f2 ntr1  = pk2(-(s1 * qx1r));
        const f2 nxqr  = pk2(-xqr);
        const f2 nxq1r = pk2(-xq1r);

        #pragma unroll
        for (int j = 0; j < 8; ++j) {
            const f2 Qx1 = __builtin_elementwise_fma(nsa, Qxq[j], uq[j]);
            const f2 xQ1 = __builtin_elementwise_fma(nsb, xQq[j], vq[j]);
            const f2 tq0 = s0v * Qxq[j];
            const f2 tq1 = s1v * Qx1;
            // w: two honest rank-1 adds
            w[j] = __builtin_elementwise_fma(Qxq[j], es0v, w[j]);
            w[j] = __builtin_elementwise_fma(Qx1,    es1v, w[j]);
            // Q row r: subtract both outer-product terms
            Q[j] = __builtin_elementwise_fma(ntr0, xQq[j], Q[j]);
            Q[j] = __builtin_elementwise_fma(ntr1, xQ1,    Q[j]);
            // QT row r (= Q column r): transposed products, identical bits
            QT[j] = __builtin_elementwise_fma(tq0, nxqr,  QT[j]);
            QT[j] = __builtin_elementwise_fma(tq1, nxq1r, QT[j]);
        }
    };

    // main rounds: t = 0,4,...,1992 -> rounds 0..1994 (prefetch <= row 1997)
    for (int t = 0; t < STEPS_ - 4; t += 4) {
        round(t + 0, xA, xB, xC, xD, 0, true);
        round(t + 2, xC, xD, xA, xB, 1, true);
    }
    // epilogue: round 1996 prefetches rows 1998,1999; round 1998 none
    round(STEPS_ - 4, xA, xB, xC, xD, 0, true);
    round(STEPS_ - 2, xC, xD, xA, xB, 1, false);

    // ---- final weights: row-group 0 holds a full replica across q ----
    if (r == 0) {
        float4* wo = (float4*)(w_out + (size_t)b * TAPS_ + qb);
        #pragma unroll
        for (int j4 = 0; j4 < 4; ++j4)
            wo[j4] = make_float4(w[2*j4].x, w[2*j4].y, w[2*j4+1].x, w[2*j4+1].y);
    }
}

extern "C" void kernel_launch(void* const* d_in, const int* in_sizes, int n_in,
                              void* d_out, int out_size, void* d_ws, size_t ws_size,
                              hipStream_t stream) {
    const float* x_seq   = (const float*)d_in[0];
    const float* d_seq   = (const float*)d_in[1];
    const float* lambdas = (const float*)d_in[2];

    float* y_out = (float*)d_out;                      // B*N floats
    float* w_out = (float*)d_out + (size_t)B_ * N_;    // B*TAPS floats

    rls_kernel<<<B_, 256, 0, stream>>>(x_seq, d_seq, lambdas, y_out, w_out);
}